// Round 4
// baseline (117.973 us; speedup 1.0000x reference)
//
#include <hip/hip_runtime.h>
#include <math.h>

typedef float f32x4 __attribute__((ext_vector_type(4)));

#define NF 69u                        // floats per output row (1 + 68)
#define WROWS 64u                     // rows per wave-tile (lane = row)
#define WTILE_FLOATS (WROWS * NF)     // 4416 floats = 17664 B per wave
#define BLOCK 256u
#define WAVES 4u

// ---------------------------------------------------------------------------
// Kernel 1: per-axis feature tables in workspace.
// tab[0 .. 5*W)        x-axis: norm,sign,sin,cos,rtan per coord
// tab[5*W .. 5*W+5*H)  y-axis
// ---------------------------------------------------------------------------
__global__ void pe_table_kernel(const int* __restrict__ hptr,
                                const int* __restrict__ wptr,
                                float* __restrict__ tab) {
    const int H = *hptr;
    const int W = *wptr;
    const int total = W + H;
    for (int i = (int)(blockIdx.x * blockDim.x + threadIdx.x); i < total;
         i += (int)(gridDim.x * blockDim.x)) {
        const bool is_y = (i >= W);
        const int c = is_y ? (i - W) : i;
        const int size = is_y ? H : W;
        double norm = 0.0, angle = 0.0;
        if (size > 1) {
            const double r = (double)c / (double)(size - 1);
            norm = 2.0 * r - 1.0;
            angle = M_PI * r;
        }
        const double d = (double)c - 0.5 * (double)size;
        const float sgn = (d > 0.0) ? 1.0f : ((d < 0.0) ? -1.0f : 0.0f);
        const int base = (is_y ? 5 * W : 0) + 5 * c;
        tab[base + 0] = (float)norm;
        tab[base + 1] = sgn;
        tab[base + 2] = (float)sin(angle);
        tab[base + 3] = (float)cos(angle);
        tab[base + 4] = (float)rint(tan(angle));
    }
}

// ---------------------------------------------------------------------------
// Kernel 2: wave-private tiles, ZERO barriers. Each wave owns a 64-row LDS
// region zeroed once; per tile it writes only 11 header floats + <=2 one-hot
// pokes per row, streams the tile out with float4 NT stores, then restores
// the pokes to zero. All ordering is intra-wave (compiler lgkmcnt); global
// stores are never drained by a barrier.
// ---------------------------------------------------------------------------
__global__ __launch_bounds__(BLOCK) void pe_main_kernel(
    const float* __restrict__ x,
    const int* __restrict__ hptr, const int* __restrict__ wptr,
    const float* __restrict__ tab,
    float* __restrict__ out, unsigned int Q /* = B*H*W rows */) {
    __shared__ __align__(16) float lds[WAVES][WTILE_FLOATS];  // 70656 B

    const unsigned int W = (unsigned int)*wptr;
    const unsigned int H = (unsigned int)*hptr;
    const unsigned int yoff = 5u * W;
    const unsigned int lane = threadIdx.x & 63u;
    const unsigned int wid = threadIdx.x >> 6;
    float* buf = lds[wid];

    // One-time zero of this wave's private buffer (wave-local, no barrier).
    {
        f32x4 z = {0.f, 0.f, 0.f, 0.f};
        f32x4* bp = (f32x4*)buf;
        for (unsigned int j = lane; j < WTILE_FLOATS / 4u; j += 64u)
            bp[j] = z;
    }

    const unsigned int ntiles = (Q + WROWS - 1u) / WROWS;
    const unsigned int gw = blockIdx.x * WAVES + wid;   // global wave id
    const unsigned int nw = gridDim.x * WAVES;

    for (unsigned int T = gw; T < ntiles; T += nw) {
        const unsigned int q = T * WROWS + lane;
        unsigned int w = 0u, h = 0u;
        const bool valid = q < Q;
        if (valid) {
            const unsigned int t = q / W;   // q = (b*H + h)*W + w
            w = q - t * W;
            h = t - (t / H) * H;
            float* row = buf + lane * NF;
            row[0] = x[q];
#pragma unroll
            for (unsigned int ft = 0u; ft < 5u; ++ft) {
                row[1u + 2u * ft] = tab[5u * w + ft];        // x-features
                row[2u + 2u * ft] = tab[yoff + 5u * h + ft]; // y-features
            }
            if (w < 29u) row[11u + w] = 1.0f;   // one-hot x poke
            if (h < 29u) row[40u + h] = 1.0f;   // one-hot y poke
        }

        // ---- stream the tile out: linear float4 NT stores ----
        const unsigned int rem = Q - T * WROWS;
        const unsigned int rows = rem < WROWS ? rem : WROWS;
        const unsigned int nfl = rows * NF;
        const unsigned int n4 = nfl >> 2;                 // full tile: 1104
        const size_t obase = (size_t)T * (size_t)WTILE_FLOATS;
        const f32x4* lp = (const f32x4*)buf;
        f32x4* op = (f32x4*)(out + obase);                // 16B-aligned
        for (unsigned int j = lane; j < n4; j += 64u)
            __builtin_nontemporal_store(lp[j], op + j);
        for (unsigned int j = (n4 << 2) + lane; j < nfl; j += 64u)
            __builtin_nontemporal_store(buf[j], out + obase + j);

        // ---- restore poked one-hot slots to zero ----
        if (valid) {
            float* row = buf + lane * NF;
            if (w < 29u) row[11u + w] = 0.0f;
            if (h < 29u) row[40u + h] = 0.0f;
        }
    }
}

extern "C" void kernel_launch(void* const* d_in, const int* in_sizes, int n_in,
                              void* d_out, int out_size, void* d_ws, size_t ws_size,
                              hipStream_t stream) {
    const float* x = (const float*)d_in[0];
    const int* hptr = (const int*)d_in[1];
    const int* wptr = (const int*)d_in[2];
    float* out = (float*)d_out;
    float* tab = (float*)d_ws;  // (W+H)*5*4 B = 20 KB for the bench shape

    pe_table_kernel<<<8, 256, 0, stream>>>(hptr, wptr, tab);

    const unsigned int Q = (unsigned int)in_sizes[0];  // B*H*W rows
    const unsigned int ntiles = (Q + WROWS - 1u) / WROWS;
    unsigned int blocks = (ntiles + WAVES - 1u) / WAVES;
    if (blocks > 2048u) blocks = 2048u;
    if (blocks == 0u) blocks = 1u;
    pe_main_kernel<<<blocks, BLOCK, 0, stream>>>(x, hptr, wptr, tab, out, Q);
}